// Round 2
// baseline (33058.951 us; speedup 1.0000x reference)
//
#include <hip/hip_runtime.h>

// Problem dims
#define TT 512
#define BB 64
#define II 256
#define HH 512
#define BH (BB * HH)           // 32768 floats per state array

// d_ws float offsets. Layout chosen so [h0_final | h1_final | c0 | c1] is one
// contiguous 131072-float block at ws[0] (T even -> final write lands in buf0),
// letting the tail of d_out be filled with a single d2d memcpy.
#define OF_H0B0 0
#define OF_H1B0 (BH)
#define OF_C0   (2 * BH)
#define OF_C1   (3 * BH)
#define OF_H0B1 (4 * BH)
#define OF_H1B1 (5 * BH)
#define WS_FLOATS (6 * BH)     // 196608 floats = 768 KB

__device__ __forceinline__ float sigf(float v) {
    return 1.0f / (1.0f + __expf(-v));
}

// One timestep: blocks [0,128) do layer 0, blocks [128,256) do layer 1.
// Each block owns 4 hidden units; thread = (b = tid&63, jj = tid>>6).
// Layer 1 reads h0 from the *read* buffer (previous step's h0) per reference.
__global__ __launch_bounds__(256, 1) void lstm_step_kernel(
    const float* __restrict__ x,
    const float* __restrict__ wih0, const float* __restrict__ whh0,
    const float* __restrict__ bih0, const float* __restrict__ bhh0,
    const float* __restrict__ pi0,  const float* __restrict__ pf0,
    const float* __restrict__ po0,
    const float* __restrict__ wih1, const float* __restrict__ whh1,
    const float* __restrict__ bih1, const float* __restrict__ bhh1,
    const float* __restrict__ pi1,  const float* __restrict__ pf1,
    const float* __restrict__ po1,
    float* __restrict__ ws, float* __restrict__ out, int t)
{
    const int tid = threadIdx.x;
    const int b   = tid & 63;
    const int jj  = tid >> 6;
    const int rp  = t & 1;

    float* const h0r = ws + (rp ? OF_H0B1 : OF_H0B0);
    float* const h1r = ws + (rp ? OF_H1B1 : OF_H1B0);
    float* const h0w = ws + (rp ? OF_H0B0 : OF_H0B1);
    float* const h1w = ws + (rp ? OF_H1B0 : OF_H1B1);
    float* const c0s = ws + OF_C0;
    float* const c1s = ws + OF_C1;

    const int blk = blockIdx.x;

    if (blk < 128) {
        // ---------------- layer 0 ----------------
        const int j = blk * 4 + jj;

        float4 A0 = {0.f, 0.f, 0.f, 0.f};
        float4 A1 = {0.f, 0.f, 0.f, 0.f};
        float4 A2 = {0.f, 0.f, 0.f, 0.f};
        float4 A3 = {0.f, 0.f, 0.f, 0.f};

        // x part: K = II
        const float4* __restrict__ xr =
            (const float4*)(x + ((size_t)t * BB + b) * II);
        const float4* __restrict__ W0 = (const float4*)(wih0 + (size_t)(0 * HH + j) * II);
        const float4* __restrict__ W1 = (const float4*)(wih0 + (size_t)(1 * HH + j) * II);
        const float4* __restrict__ W2 = (const float4*)(wih0 + (size_t)(2 * HH + j) * II);
        const float4* __restrict__ W3 = (const float4*)(wih0 + (size_t)(3 * HH + j) * II);
#pragma unroll 4
        for (int k = 0; k < II / 4; ++k) {
            const float4 xv = xr[k];
            const float4 w0 = W0[k], w1 = W1[k], w2 = W2[k], w3 = W3[k];
            A0.x += xv.x * w0.x; A0.y += xv.y * w0.y; A0.z += xv.z * w0.z; A0.w += xv.w * w0.w;
            A1.x += xv.x * w1.x; A1.y += xv.y * w1.y; A1.z += xv.z * w1.z; A1.w += xv.w * w1.w;
            A2.x += xv.x * w2.x; A2.y += xv.y * w2.y; A2.z += xv.z * w2.z; A2.w += xv.w * w2.w;
            A3.x += xv.x * w3.x; A3.y += xv.y * w3.y; A3.z += xv.z * w3.z; A3.w += xv.w * w3.w;
        }

        // h part: K = HH
        const float4* __restrict__ hr = (const float4*)(h0r + b * HH);
        const float4* __restrict__ U0 = (const float4*)(whh0 + (size_t)(0 * HH + j) * HH);
        const float4* __restrict__ U1 = (const float4*)(whh0 + (size_t)(1 * HH + j) * HH);
        const float4* __restrict__ U2 = (const float4*)(whh0 + (size_t)(2 * HH + j) * HH);
        const float4* __restrict__ U3 = (const float4*)(whh0 + (size_t)(3 * HH + j) * HH);
#pragma unroll 4
        for (int k = 0; k < HH / 4; ++k) {
            const float4 hv = hr[k];
            const float4 w0 = U0[k], w1 = U1[k], w2 = U2[k], w3 = U3[k];
            A0.x += hv.x * w0.x; A0.y += hv.y * w0.y; A0.z += hv.z * w0.z; A0.w += hv.w * w0.w;
            A1.x += hv.x * w1.x; A1.y += hv.y * w1.y; A1.z += hv.z * w1.z; A1.w += hv.w * w1.w;
            A2.x += hv.x * w2.x; A2.y += hv.y * w2.y; A2.z += hv.z * w2.z; A2.w += hv.w * w2.w;
            A3.x += hv.x * w3.x; A3.y += hv.y * w3.y; A3.z += hv.z * w3.z; A3.w += hv.w * w3.w;
        }

        const float a0 = A0.x + A0.y + A0.z + A0.w + bih0[0 * HH + j] + bhh0[0 * HH + j];
        const float a1 = A1.x + A1.y + A1.z + A1.w + bih0[1 * HH + j] + bhh0[1 * HH + j];
        const float a2 = A2.x + A2.y + A2.z + A2.w + bih0[2 * HH + j] + bhh0[2 * HH + j];
        const float a3 = A3.x + A3.y + A3.z + A3.w + bih0[3 * HH + j] + bhh0[3 * HH + j];

        const float c  = c0s[b * HH + j];
        const float ig = sigf(a0 + c * pi0[j]);
        const float fg = sigf(a1 + c * pf0[j]);
        const float gg = tanhf(a2);
        const float og = sigf(a3 + c * po0[j]);   // peephole on OLD c per reference
        const float cn = fg * c + ig * gg;
        const float hn = og * tanhf(cn);

        c0s[b * HH + j] = cn;
        h0w[b * HH + j] = hn;
    } else {
        // ---------------- layer 1 ----------------
        const int j = (blk - 128) * 4 + jj;

        float4 A0 = {0.f, 0.f, 0.f, 0.f};
        float4 A1 = {0.f, 0.f, 0.f, 0.f};
        float4 A2 = {0.f, 0.f, 0.f, 0.f};
        float4 A3 = {0.f, 0.f, 0.f, 0.f};

        // input part: previous h0 (read buffer), K = HH
        const float4* __restrict__ hr0 = (const float4*)(h0r + b * HH);
        const float4* __restrict__ W0 = (const float4*)(wih1 + (size_t)(0 * HH + j) * HH);
        const float4* __restrict__ W1 = (const float4*)(wih1 + (size_t)(1 * HH + j) * HH);
        const float4* __restrict__ W2 = (const float4*)(wih1 + (size_t)(2 * HH + j) * HH);
        const float4* __restrict__ W3 = (const float4*)(wih1 + (size_t)(3 * HH + j) * HH);
#pragma unroll 4
        for (int k = 0; k < HH / 4; ++k) {
            const float4 hv = hr0[k];
            const float4 w0 = W0[k], w1 = W1[k], w2 = W2[k], w3 = W3[k];
            A0.x += hv.x * w0.x; A0.y += hv.y * w0.y; A0.z += hv.z * w0.z; A0.w += hv.w * w0.w;
            A1.x += hv.x * w1.x; A1.y += hv.y * w1.y; A1.z += hv.z * w1.z; A1.w += hv.w * w1.w;
            A2.x += hv.x * w2.x; A2.y += hv.y * w2.y; A2.z += hv.z * w2.z; A2.w += hv.w * w2.w;
            A3.x += hv.x * w3.x; A3.y += hv.y * w3.y; A3.z += hv.z * w3.z; A3.w += hv.w * w3.w;
        }

        // recurrent part: previous h1, K = HH
        const float4* __restrict__ hr1 = (const float4*)(h1r + b * HH);
        const float4* __restrict__ U0 = (const float4*)(whh1 + (size_t)(0 * HH + j) * HH);
        const float4* __restrict__ U1 = (const float4*)(whh1 + (size_t)(1 * HH + j) * HH);
        const float4* __restrict__ U2 = (const float4*)(whh1 + (size_t)(2 * HH + j) * HH);
        const float4* __restrict__ U3 = (const float4*)(whh1 + (size_t)(3 * HH + j) * HH);
#pragma unroll 4
        for (int k = 0; k < HH / 4; ++k) {
            const float4 hv = hr1[k];
            const float4 w0 = U0[k], w1 = U1[k], w2 = U2[k], w3 = U3[k];
            A0.x += hv.x * w0.x; A0.y += hv.y * w0.y; A0.z += hv.z * w0.z; A0.w += hv.w * w0.w;
            A1.x += hv.x * w1.x; A1.y += hv.y * w1.y; A1.z += hv.z * w1.z; A1.w += hv.w * w1.w;
            A2.x += hv.x * w2.x; A2.y += hv.y * w2.y; A2.z += hv.z * w2.z; A2.w += hv.w * w2.w;
            A3.x += hv.x * w3.x; A3.y += hv.y * w3.y; A3.z += hv.z * w3.z; A3.w += hv.w * w3.w;
        }

        const float a0 = A0.x + A0.y + A0.z + A0.w + bih1[0 * HH + j] + bhh1[0 * HH + j];
        const float a1 = A1.x + A1.y + A1.z + A1.w + bih1[1 * HH + j] + bhh1[1 * HH + j];
        const float a2 = A2.x + A2.y + A2.z + A2.w + bih1[2 * HH + j] + bhh1[2 * HH + j];
        const float a3 = A3.x + A3.y + A3.z + A3.w + bih1[3 * HH + j] + bhh1[3 * HH + j];

        const float c  = c1s[b * HH + j];
        const float ig = sigf(a0 + c * pi1[j]);
        const float fg = sigf(a1 + c * pf1[j]);
        const float gg = tanhf(a2);
        const float og = sigf(a3 + c * po1[j]);
        const float cn = fg * c + ig * gg;
        const float hn = og * tanhf(cn);

        c1s[b * HH + j] = cn;
        h1w[b * HH + j] = hn;
        out[(size_t)t * BH + b * HH + j] = hn;   // outputs[t] = h1_new
    }
}

extern "C" void kernel_launch(void* const* d_in, const int* in_sizes, int n_in,
                              void* d_out, int out_size, void* d_ws, size_t ws_size,
                              hipStream_t stream) {
    (void)in_sizes; (void)n_in; (void)out_size; (void)ws_size;

    const float* x    = (const float*)d_in[0];
    const float* wih0 = (const float*)d_in[1];
    const float* whh0 = (const float*)d_in[2];
    const float* bih0 = (const float*)d_in[3];
    const float* bhh0 = (const float*)d_in[4];
    const float* pi0  = (const float*)d_in[5];
    const float* pf0  = (const float*)d_in[6];
    const float* po0  = (const float*)d_in[7];
    const float* wih1 = (const float*)d_in[8];
    const float* whh1 = (const float*)d_in[9];
    const float* bih1 = (const float*)d_in[10];
    const float* bhh1 = (const float*)d_in[11];
    const float* pi1  = (const float*)d_in[12];
    const float* pf1  = (const float*)d_in[13];
    const float* po1  = (const float*)d_in[14];

    float* ws  = (float*)d_ws;
    float* out = (float*)d_out;

    // Zero initial states: h0 buf0, h1 buf0, c0, c1 (first 131072 floats).
    // d_ws is re-poisoned 0xAA before every timed call, so this must run
    // inside the captured graph (memset node).
    hipMemsetAsync(ws, 0, (size_t)(4 * BH) * sizeof(float), stream);

    for (int t = 0; t < TT; ++t) {
        lstm_step_kernel<<<256, 256, 0, stream>>>(
            x, wih0, whh0, bih0, bhh0, pi0, pf0, po0,
            wih1, whh1, bih1, bhh1, pi1, pf1, po1,
            ws, out, t);
    }

    // T even -> final h0/h1 are in buf0 = ws[0 .. 2*BH), c0/c1 follow at
    // ws[2*BH .. 4*BH). This matches d_out tail layout [h_n | c_n] exactly.
    hipMemcpyAsync(out + (size_t)TT * BH, ws, (size_t)(4 * BH) * sizeof(float),
                   hipMemcpyDeviceToDevice, stream);
}

// Round 3
// 18328.268 us; speedup vs baseline: 1.8037x; 1.8037x over previous
//
#include <hip/hip_runtime.h>

// Problem dims
#define TT 512
#define BB 64
#define II 256
#define HH 512
#define BH (BB * HH)            // 32768 floats

// ws float offsets.
// [h0b0 | h1b0] contiguous -> final h_n memcpy source (t=511 writes parity 0).
// cT0/cT1 are TRANSPOSED [H][B] (owner-wave coalesced access), fixed up at end.
#define OF_H0B0 0
#define OF_H1B0 (BH)
#define OF_CT0  (2 * BH)
#define OF_CT1  (3 * BH)
#define OF_H0B1 (4 * BH)
#define OF_H1B1 (5 * BH)

__device__ __forceinline__ float sigf(float v) {
    return 1.0f / (1.0f + __expf(-v));
}

// One timestep. 256 blocks x 256 threads.
// Blocks [0,128): layer 0. Blocks [128,256): layer 1.
// Block owns 4 hidden units j (one per wave, wave-uniform); lane = batch b.
// Activations (x rows / h rows) are staged per 128-k chunk into LDS
// (double-buffered, XOR-swizzled) so compute reads are conflict-free
// ds_read_b128 and all global reads are coalesced.
__global__ __launch_bounds__(256, 1) void lstm_step(
    const float* __restrict__ x,
    const float* __restrict__ wih0, const float* __restrict__ whh0,
    const float* __restrict__ bih0, const float* __restrict__ bhh0,
    const float* __restrict__ pi0,  const float* __restrict__ pf0,
    const float* __restrict__ po0,
    const float* __restrict__ wih1, const float* __restrict__ whh1,
    const float* __restrict__ bih1, const float* __restrict__ bhh1,
    const float* __restrict__ pi1,  const float* __restrict__ pf1,
    const float* __restrict__ po1,
    float* __restrict__ ws, float* __restrict__ out, int t)
{
    // 2 buffers x 64 b-rows x 32 float4 granules (=128 k) = 64 KB
    __shared__ float4 lds4[2][64 * 32];

    const int tid = threadIdx.x;
    const int b   = tid & 63;
    const int jju = __builtin_amdgcn_readfirstlane(tid >> 6);  // wave id 0..3
    const int blk = blockIdx.x;
    const int L   = blk >> 7;            // layer 0/1
    const int jb  = blk & 127;
    const int j   = jb * 4 + jju;        // hidden unit, wave-uniform

    const int rp = t & 1;
    const float* __restrict__ h0r = ws + (rp ? OF_H0B1 : OF_H0B0);
    const float* __restrict__ h1r = ws + (rp ? OF_H1B1 : OF_H1B0);
    float* __restrict__ h0w = ws + (rp ? OF_H0B0 : OF_H0B1);
    float* __restrict__ h1w = ws + (rp ? OF_H1B0 : OF_H1B1);
    float* __restrict__ cT  = ws + (L ? OF_CT1 : OF_CT0);

    const int NC     = L ? 8 : 6;        // 128-k chunks (L0: 256 x + 512 h; L1: 512 + 512)
    const int firstB = L ? 4 : 2;        // first chunk index using the hh matrix

    const float* __restrict__ WA = L ? wih1 : wih0;   // rowlen L?512:256
    const float* __restrict__ WB = L ? whh1 : whh0;   // rowlen 512
    const int rlA = L ? HH : II;

    // staging thread mapping: thread holds 8 granules (4 consecutive k) of row sb
    const int sb  = tid >> 2;            // 0..63 (b-row being staged)
    const int skf = tid & 3;

    float4 sreg0, sreg1, sreg2, sreg3, sreg4, sreg5, sreg6, sreg7;

    const float* srow_for = nullptr;     // set per chunk in STAGE_LOAD

#define STAGE_LOAD(c)                                                        \
    {                                                                        \
        const float* srow;                                                   \
        if (L == 0) {                                                        \
            if ((c) < 2) srow = x + ((size_t)t * BB + sb) * II + (c) * 128;  \
            else         srow = h0r + (size_t)sb * HH + ((c) - 2) * 128;     \
        } else {                                                             \
            if ((c) < 4) srow = h0r + (size_t)sb * HH + (c) * 128;           \
            else         srow = h1r + (size_t)sb * HH + ((c) - 4) * 128;     \
        }                                                                    \
        sreg0 = *(const float4*)(srow + (skf + 4 * 0) * 4);                  \
        sreg1 = *(const float4*)(srow + (skf + 4 * 1) * 4);                  \
        sreg2 = *(const float4*)(srow + (skf + 4 * 2) * 4);                  \
        sreg3 = *(const float4*)(srow + (skf + 4 * 3) * 4);                  \
        sreg4 = *(const float4*)(srow + (skf + 4 * 4) * 4);                  \
        sreg5 = *(const float4*)(srow + (skf + 4 * 5) * 4);                  \
        sreg6 = *(const float4*)(srow + (skf + 4 * 6) * 4);                  \
        sreg7 = *(const float4*)(srow + (skf + 4 * 7) * 4);                  \
    }

#define STAGE_WRITE(buf)                                                     \
    {                                                                        \
        const int sw = sb & 7;                                               \
        float4* Lw = &lds4[(buf)][sb * 32];                                  \
        Lw[(skf + 4 * 0) ^ sw] = sreg0;                                      \
        Lw[(skf + 4 * 1) ^ sw] = sreg1;                                      \
        Lw[(skf + 4 * 2) ^ sw] = sreg2;                                      \
        Lw[(skf + 4 * 3) ^ sw] = sreg3;                                      \
        Lw[(skf + 4 * 4) ^ sw] = sreg4;                                      \
        Lw[(skf + 4 * 5) ^ sw] = sreg5;                                      \
        Lw[(skf + 4 * 6) ^ sw] = sreg6;                                      \
        Lw[(skf + 4 * 7) ^ sw] = sreg7;                                      \
    }

    (void)srow_for;

    float4 A0 = {0, 0, 0, 0}, A1 = {0, 0, 0, 0};
    float4 A2 = {0, 0, 0, 0}, A3 = {0, 0, 0, 0};

    // prologue: stage chunk 0 into buf 0
    STAGE_LOAD(0);
    STAGE_WRITE(0);

    const int swz   = b & 7;
    const float4* __restrict__ LbBase0 = &lds4[0][b * 32];
    const float4* __restrict__ LbBase1 = &lds4[1][b * 32];

    for (int c = 0; c < NC; ++c) {
        // uniform weight row pointers for this chunk (j, c, L all wave-uniform)
        const float4 *Wp0, *Wp1, *Wp2, *Wp3;
        if (c < firstB) {
            const int koff = c * 128;
            Wp0 = (const float4*)(WA + (size_t)(0 * HH + j) * rlA + koff);
            Wp1 = (const float4*)(WA + (size_t)(1 * HH + j) * rlA + koff);
            Wp2 = (const float4*)(WA + (size_t)(2 * HH + j) * rlA + koff);
            Wp3 = (const float4*)(WA + (size_t)(3 * HH + j) * rlA + koff);
        } else {
            const int koff = (c - firstB) * 128;
            Wp0 = (const float4*)(WB + (size_t)(0 * HH + j) * HH + koff);
            Wp1 = (const float4*)(WB + (size_t)(1 * HH + j) * HH + koff);
            Wp2 = (const float4*)(WB + (size_t)(2 * HH + j) * HH + koff);
            Wp3 = (const float4*)(WB + (size_t)(3 * HH + j) * HH + koff);
        }

        if (c + 1 < NC) STAGE_LOAD(c + 1);   // issue next-chunk global loads early

        __syncthreads();                     // buf[c&1] fully written; other buf free

        const float4* __restrict__ Lb = (c & 1) ? LbBase1 : LbBase0;
#pragma unroll 4
        for (int kk = 0; kk < 32; ++kk) {
            const float4 h4 = Lb[kk ^ swz];
            const float4 w0 = Wp0[kk], w1 = Wp1[kk], w2 = Wp2[kk], w3 = Wp3[kk];
            A0.x += h4.x * w0.x; A0.y += h4.y * w0.y; A0.z += h4.z * w0.z; A0.w += h4.w * w0.w;
            A1.x += h4.x * w1.x; A1.y += h4.y * w1.y; A1.z += h4.z * w1.z; A1.w += h4.w * w1.w;
            A2.x += h4.x * w2.x; A2.y += h4.y * w2.y; A2.z += h4.z * w2.z; A2.w += h4.w * w2.w;
            A3.x += h4.x * w3.x; A3.y += h4.y * w3.y; A3.z += h4.z * w3.z; A3.w += h4.w * w3.w;
        }

        if (c + 1 < NC) STAGE_WRITE((c + 1) & 1);  // other buffer — safe (see barrier)
    }

    // ---- epilogue: gate math ----
    const float* __restrict__ bih = L ? bih1 : bih0;
    const float* __restrict__ bhh = L ? bhh1 : bhh0;
    const float* __restrict__ pi  = L ? pi1 : pi0;
    const float* __restrict__ pf  = L ? pf1 : pf0;
    const float* __restrict__ po  = L ? po1 : po0;

    const float a0 = A0.x + A0.y + A0.z + A0.w + bih[0 * HH + j] + bhh[0 * HH + j];
    const float a1 = A1.x + A1.y + A1.z + A1.w + bih[1 * HH + j] + bhh[1 * HH + j];
    const float a2 = A2.x + A2.y + A2.z + A2.w + bih[2 * HH + j] + bhh[2 * HH + j];
    const float a3 = A3.x + A3.y + A3.z + A3.w + bih[3 * HH + j] + bhh[3 * HH + j];

    const float c_old = cT[j * 64 + b];          // coalesced (transposed c)
    const float ig = sigf(a0 + c_old * pi[j]);
    const float fg = sigf(a1 + c_old * pf[j]);
    const float gg = tanhf(a2);
    const float og = sigf(a3 + c_old * po[j]);   // peephole on OLD c per reference
    const float cn = fg * c_old + ig * gg;
    const float hn = og * tanhf(cn);

    cT[j * 64 + b] = cn;
    if (L == 0) {
        h0w[(size_t)b * HH + j] = hn;            // scatter store (once/step, cheap)
    } else {
        h1w[(size_t)b * HH + j] = hn;
        out[(size_t)t * BH + (size_t)b * HH + j] = hn;
    }
#undef STAGE_LOAD
#undef STAGE_WRITE
}

// Transpose cT [2][H][B] -> out tail c_n [2][B][H]
__global__ __launch_bounds__(256, 1) void cn_fixup(const float* __restrict__ ws,
                                                   float* __restrict__ out)
{
    const int idx = blockIdx.x * 256 + threadIdx.x;   // 0..65535
    const int l = idx >> 15;
    const int r = idx & 32767;
    const int jrow = r >> 6;
    const int b = r & 63;
    const float v = ws[(l ? OF_CT1 : OF_CT0) + jrow * 64 + b];  // coalesced read
    out[(size_t)TT * BH + 2 * BH + (size_t)l * BH + (size_t)b * HH + jrow] = v;
}

extern "C" void kernel_launch(void* const* d_in, const int* in_sizes, int n_in,
                              void* d_out, int out_size, void* d_ws, size_t ws_size,
                              hipStream_t stream) {
    (void)in_sizes; (void)n_in; (void)out_size; (void)ws_size;

    const float* x    = (const float*)d_in[0];
    const float* wih0 = (const float*)d_in[1];
    const float* whh0 = (const float*)d_in[2];
    const float* bih0 = (const float*)d_in[3];
    const float* bhh0 = (const float*)d_in[4];
    const float* pi0  = (const float*)d_in[5];
    const float* pf0  = (const float*)d_in[6];
    const float* po0  = (const float*)d_in[7];
    const float* wih1 = (const float*)d_in[8];
    const float* whh1 = (const float*)d_in[9];
    const float* bih1 = (const float*)d_in[10];
    const float* bhh1 = (const float*)d_in[11];
    const float* pi1  = (const float*)d_in[12];
    const float* pf1  = (const float*)d_in[13];
    const float* po1  = (const float*)d_in[14];

    float* ws  = (float*)d_ws;
    float* out = (float*)d_out;

    // Zero h0b0, h1b0, cT0, cT1 (first 4*BH floats). Buf1 h arrays are written
    // at t=0 before ever being read.
    hipMemsetAsync(ws, 0, (size_t)(4 * BH) * sizeof(float), stream);

    for (int t = 0; t < TT; ++t) {
        lstm_step<<<256, 256, 0, stream>>>(
            x, wih0, whh0, bih0, bhh0, pi0, pf0, po0,
            wih1, whh1, bih1, bhh1, pi1, pf1, po1,
            ws, out, t);
    }

    // h_n: t=511 (odd) writes into buf0 -> [h0b0 | h1b0] is exactly [2][B][H].
    hipMemcpyAsync(out + (size_t)TT * BH, ws, (size_t)(2 * BH) * sizeof(float),
                   hipMemcpyDeviceToDevice, stream);
    // c_n: transpose fixup
    cn_fixup<<<256, 256, 0, stream>>>(ws, out);
}

// Round 4
// 17835.397 us; speedup vs baseline: 1.8536x; 1.0276x over previous
//
#include <hip/hip_runtime.h>

// Problem dims
#define TT 512
#define BB 64
#define II 256
#define HH 512
#define BH (BB * HH)            // 32768 floats

// ws float offsets. [h0b0 | h1b0] contiguous -> final h_n memcpy source
// (t=511 odd writes parity 0). cT0/cT1 are TRANSPOSED [H][B], fixed up at end.
#define OF_H0B0 0
#define OF_H1B0 (BH)
#define OF_CT0  (2 * BH)
#define OF_CT1  (3 * BH)
#define OF_H0B1 (4 * BH)
#define OF_H1B1 (5 * BH)

__device__ __forceinline__ float sigf(float v) {
    return 1.0f / (1.0f + __expf(-v));
}

// XOR swizzle within 32-granule (512 B) blocks: spreads the 64 lanes'
// same-granule/different-row reads across all banks (fixes round-3's 8-way
// conflict from ^(b&7)).
#define SWZ(g, r) ((((g) & ~31)) | ((((g) & 31)) ^ ((r) & 31)))

// One timestep. 256 blocks x 1024 threads (16 waves = 4 j x 4 k-quarters).
// Blocks [0,128): layer 0. Blocks [128,256): layer 1. 1 block/CU, 4 waves/SIMD.
// Phases stage 256k (or 128k) of the concatenated [input; hidden] stream into
// a double-buffered LDS tile; all 16 waves compute their K-slice concurrently;
// K-partials combine via LDS; ksq==0 waves do gate math + stores.
__global__ __launch_bounds__(1024, 4) void lstm_step(
    const float* __restrict__ x,
    const float* __restrict__ wih0, const float* __restrict__ whh0,
    const float* __restrict__ bih0, const float* __restrict__ bhh0,
    const float* __restrict__ pi0,  const float* __restrict__ pf0,
    const float* __restrict__ po0,
    const float* __restrict__ wih1, const float* __restrict__ whh1,
    const float* __restrict__ bih1, const float* __restrict__ bhh1,
    const float* __restrict__ pi1,  const float* __restrict__ pf1,
    const float* __restrict__ po1,
    float* __restrict__ ws, float* __restrict__ out, int t)
{
    __shared__ float4 buf[2][64 * 64];        // 2 x 64 KB phase buffers
    __shared__ float  comb[4][4][4][64];      // [jj][ksq][gate][b] 16 KB

    const int tid = threadIdx.x;
    const int b   = tid & 63;
    const int wv  = tid >> 6;                              // 0..15
    const int jj  = __builtin_amdgcn_readfirstlane(wv >> 2);   // 0..3
    const int ksq = __builtin_amdgcn_readfirstlane(wv & 3);    // 0..3
    const int blk = blockIdx.x;
    const int L   = blk >> 7;
    const int j   = (blk & 127) * 4 + jj;

    const int rp = t & 1;
    const float* __restrict__ h0r = ws + (rp ? OF_H0B1 : OF_H0B0);
    const float* __restrict__ h1r = ws + (rp ? OF_H1B1 : OF_H1B0);
    float* __restrict__ h0w = ws + (rp ? OF_H0B0 : OF_H0B1);
    float* __restrict__ h1w = ws + (rp ? OF_H1B0 : OF_H1B1);
    float* __restrict__ cT  = ws + (L ? OF_CT1 : OF_CT0);

    // L0: 5 phases over [x(256) | h0(512)]: nk = 256,128,128,128,128
    // L1: 4 phases over [h0(512) | h1(512)]: nk = 256 each
    const int NP = L ? 4 : 5;
#define PH_NK(p) (L ? 256 : ((p) == 0 ? 256 : 128))
#define PH_SRC(p)                                                          \
    (L == 0 ? ((p) == 0 ? x + ((size_t)t * BB + sr) * II                   \
                        : h0r + (size_t)sr * HH + ((p) - 1) * 128)         \
            : ((p) < 2 ? h0r + (size_t)sr * HH + (p) * 256                 \
                       : h1r + (size_t)sr * HH + ((p) - 2) * 256))

    // staging mapping: 16 threads per b-row, each loads 2 or 4 float4s
    const int sr = tid >> 4;          // staged row (b) 0..63
    const int sf = tid & 15;

    float4 sreg0, sreg1, sreg2, sreg3;
    sreg2 = make_float4(0.f, 0.f, 0.f, 0.f);
    sreg3 = sreg2;

#define STAGE_LOAD(p)                                                      \
    {                                                                      \
        const int nk_ = PH_NK(p);                                          \
        const float* __restrict__ src_ = PH_SRC(p);                        \
        sreg0 = *(const float4*)(src_ + 4 * sf);                           \
        sreg1 = *(const float4*)(src_ + 4 * (sf + 16));                    \
        if (nk_ == 256) {                                                  \
            sreg2 = *(const float4*)(src_ + 4 * (sf + 32));                \
            sreg3 = *(const float4*)(src_ + 4 * (sf + 48));                \
        }                                                                  \
    }

#define STAGE_WRITE(p, bb)                                                 \
    {                                                                      \
        const int nk_ = PH_NK(p);                                          \
        const int rs_ = nk_ >> 2;                                          \
        float4* __restrict__ B_ = &buf[bb][(size_t)sr * rs_];              \
        B_[SWZ(sf, sr)]      = sreg0;                                      \
        B_[SWZ(sf + 16, sr)] = sreg1;                                      \
        if (nk_ == 256) {                                                  \
            B_[SWZ(sf + 32, sr)] = sreg2;                                  \
            B_[SWZ(sf + 48, sr)] = sreg3;                                  \
        }                                                                  \
    }

    float4 A0 = {0, 0, 0, 0}, A1 = {0, 0, 0, 0};
    float4 A2 = {0, 0, 0, 0}, A3 = {0, 0, 0, 0};

#define COMPUTE(p, bb)                                                         \
    {                                                                          \
        const int nk_  = PH_NK(p);                                             \
        const int GRW_ = nk_ >> 4;  /* granules per wave: 16 or 8 */           \
        const int rs_  = nk_ >> 2;  /* row stride in granules */               \
        const float* W_; int rowlen_, koff_;                                   \
        if (L == 0) {                                                          \
            if ((p) == 0) { W_ = wih0; rowlen_ = II; koff_ = ksq * 64; }       \
            else { W_ = whh0; rowlen_ = HH; koff_ = ((p) - 1) * 128 + ksq * 32; } \
        } else {                                                               \
            if ((p) < 2) { W_ = wih1; rowlen_ = HH; koff_ = (p) * 256 + ksq * 64; } \
            else { W_ = whh1; rowlen_ = HH; koff_ = ((p) - 2) * 256 + ksq * 64; } \
        }                                                                      \
        const float4* __restrict__ Wp0_ =                                      \
            (const float4*)(W_ + (size_t)(0 * HH + j) * rowlen_ + koff_);      \
        const float4* __restrict__ Wp1_ =                                      \
            (const float4*)(W_ + (size_t)(1 * HH + j) * rowlen_ + koff_);      \
        const float4* __restrict__ Wp2_ =                                      \
            (const float4*)(W_ + (size_t)(2 * HH + j) * rowlen_ + koff_);      \
        const float4* __restrict__ Wp3_ =                                      \
            (const float4*)(W_ + (size_t)(3 * HH + j) * rowlen_ + koff_);      \
        const float4* __restrict__ Bb_ = &buf[bb][(size_t)b * rs_];            \
        const int g0_ = ksq * GRW_;                                            \
        _Pragma("unroll 2")                                                    \
        for (int i_ = 0; i_ < GRW_; ++i_) {                                    \
            const int g_ = g0_ + i_;                                           \
            const float4 h4 = Bb_[SWZ(g_, b)];                                 \
            const float4 w0 = Wp0_[i_], w1 = Wp1_[i_], w2 = Wp2_[i_], w3 = Wp3_[i_]; \
            A0.x += h4.x * w0.x; A0.y += h4.y * w0.y; A0.z += h4.z * w0.z; A0.w += h4.w * w0.w; \
            A1.x += h4.x * w1.x; A1.y += h4.y * w1.y; A1.z += h4.z * w1.z; A1.w += h4.w * w1.w; \
            A2.x += h4.x * w2.x; A2.y += h4.y * w2.y; A2.z += h4.z * w2.z; A2.w += h4.w * w2.w; \
            A3.x += h4.x * w3.x; A3.y += h4.y * w3.y; A3.z += h4.z * w3.z; A3.w += h4.w * w3.w; \
        }                                                                      \
    }

    // prologue: stage phase 0 into buf 0 (loads + writes, then loop barrier)
    STAGE_LOAD(0);
    STAGE_WRITE(0, 0);

    for (int p = 0; p < NP; ++p) {
        __syncthreads();                      // buf[p&1] fully written
        if (p + 1 < NP) STAGE_LOAD(p + 1);    // AFTER barrier -> overlaps compute
        COMPUTE(p, p & 1);
        if (p + 1 < NP) STAGE_WRITE(p + 1, (p + 1) & 1);  // waits vmcnt here, not at barrier
    }

    // ---- K-partial combine ----
    comb[jj][ksq][0][b] = A0.x + A0.y + A0.z + A0.w;
    comb[jj][ksq][1][b] = A1.x + A1.y + A1.z + A1.w;
    comb[jj][ksq][2][b] = A2.x + A2.y + A2.z + A2.w;
    comb[jj][ksq][3][b] = A3.x + A3.y + A3.z + A3.w;
    __syncthreads();

    if (ksq == 0) {
        const float* __restrict__ bih = L ? bih1 : bih0;
        const float* __restrict__ bhh = L ? bhh1 : bhh0;
        const float* __restrict__ pi  = L ? pi1 : pi0;
        const float* __restrict__ pf  = L ? pf1 : pf0;
        const float* __restrict__ po  = L ? po1 : po0;

        const float a0 = comb[jj][0][0][b] + comb[jj][1][0][b] + comb[jj][2][0][b] + comb[jj][3][0][b]
                       + bih[0 * HH + j] + bhh[0 * HH + j];
        const float a1 = comb[jj][0][1][b] + comb[jj][1][1][b] + comb[jj][2][1][b] + comb[jj][3][1][b]
                       + bih[1 * HH + j] + bhh[1 * HH + j];
        const float a2 = comb[jj][0][2][b] + comb[jj][1][2][b] + comb[jj][2][2][b] + comb[jj][3][2][b]
                       + bih[2 * HH + j] + bhh[2 * HH + j];
        const float a3 = comb[jj][0][3][b] + comb[jj][1][3][b] + comb[jj][2][3][b] + comb[jj][3][3][b]
                       + bih[3 * HH + j] + bhh[3 * HH + j];

        const float c_old = cT[j * 64 + b];          // coalesced (transposed c)
        const float ig = sigf(a0 + c_old * pi[j]);
        const float fg = sigf(a1 + c_old * pf[j]);
        const float gg = tanhf(a2);
        const float og = sigf(a3 + c_old * po[j]);   // peephole on OLD c per reference
        const float cn = fg * c_old + ig * gg;
        const float hn = og * tanhf(cn);

        cT[j * 64 + b] = cn;
        if (L == 0) {
            h0w[(size_t)b * HH + j] = hn;            // scatter store, once/step
        } else {
            h1w[(size_t)b * HH + j] = hn;
            out[(size_t)t * BH + (size_t)b * HH + j] = hn;
        }
    }
#undef PH_NK
#undef PH_SRC
#undef STAGE_LOAD
#undef STAGE_WRITE
#undef COMPUTE
}

// Transpose cT [2][H][B] -> out tail c_n [2][B][H]
__global__ __launch_bounds__(256, 1) void cn_fixup(const float* __restrict__ ws,
                                                   float* __restrict__ out)
{
    const int idx = blockIdx.x * 256 + threadIdx.x;   // 0..65535
    const int l = idx >> 15;
    const int r = idx & 32767;
    const int jrow = r >> 6;
    const int b = r & 63;
    const float v = ws[(l ? OF_CT1 : OF_CT0) + jrow * 64 + b];  // coalesced read
    out[(size_t)TT * BH + 2 * BH + (size_t)l * BH + (size_t)b * HH + jrow] = v;
}

extern "C" void kernel_launch(void* const* d_in, const int* in_sizes, int n_in,
                              void* d_out, int out_size, void* d_ws, size_t ws_size,
                              hipStream_t stream) {
    (void)in_sizes; (void)n_in; (void)out_size; (void)ws_size;

    const float* x    = (const float*)d_in[0];
    const float* wih0 = (const float*)d_in[1];
    const float* whh0 = (const float*)d_in[2];
    const float* bih0 = (const float*)d_in[3];
    const float* bhh0 = (const float*)d_in[4];
    const float* pi0  = (const float*)d_in[5];
    const float* pf0  = (const float*)d_in[6];
    const float* po0  = (const float*)d_in[7];
    const float* wih1 = (const float*)d_in[8];
    const float* whh1 = (const float*)d_in[9];
    const float* bih1 = (const float*)d_in[10];
    const float* bhh1 = (const float*)d_in[11];
    const float* pi1  = (const float*)d_in[12];
    const float* pf1  = (const float*)d_in[13];
    const float* po1  = (const float*)d_in[14];

    float* ws  = (float*)d_ws;
    float* out = (float*)d_out;

    // Zero h0b0, h1b0, cT0, cT1 (first 4*BH floats). Buf1 h arrays are written
    // at t=0 before ever being read. ws is re-poisoned before every timed call,
    // so this memset must be inside the captured graph.
    hipMemsetAsync(ws, 0, (size_t)(4 * BH) * sizeof(float), stream);

    for (int t = 0; t < TT; ++t) {
        lstm_step<<<256, 1024, 0, stream>>>(
            x, wih0, whh0, bih0, bhh0, pi0, pf0, po0,
            wih1, whh1, bih1, bhh1, pi1, pf1, po1,
            ws, out, t);
    }

    // h_n: t=511 (odd) writes into buf0 -> [h0b0 | h1b0] is exactly [2][B][H].
    hipMemcpyAsync(out + (size_t)TT * BH, ws, (size_t)(2 * BH) * sizeof(float),
                   hipMemcpyDeviceToDevice, stream);
    // c_n: transpose fixup
    cn_fixup<<<256, 256, 0, stream>>>(ws, out);
}